// Round 11
// baseline (150.249 us; speedup 1.0000x reference)
//
#include <hip/hip_runtime.h>
#include <hip/hip_bf16.h>

#define N_PTS  4096
#define M_Q    16384
#define C_IN   256
#define C_SKIP 128
#define C_H    384      // C_IN + C_SKIP
#define HDIM   256
#define QB     32       // queries per block -> 512 blocks = 2/CU, 16 waves/CU
#define CANDMAX 24
#define EPSW   4e-3f    // capture window >= 2x worst-case MFMA d' error (~4e-4)

typedef __bf16 bf16x8 __attribute__((ext_vector_type(8)));
typedef float  f32x4  __attribute__((ext_vector_type(4)));

// prep segment boundaries
#define PW1  (C_H*HDIM)                    //  98304
#define PW2  (PW1 + HDIM*HDIM)             // 163840
#define PPV  (PW2 + N_PTS)                 // 167936
#define PAQ  (PPV + M_Q)                   // 184320

__device__ __forceinline__ unsigned short bfbits(float v) {
    __hip_bfloat16 b = __float2bfloat16(v);
    return *(unsigned short*)&b;
}
__device__ __forceinline__ float bff(unsigned short u) {
    __hip_bfloat16 b = *(__hip_bfloat16*)&u;
    return __bfloat162float(b);
}
// 3-way bf16 split: v = h + m + l + O(2^-27 v)
__device__ __forceinline__ void split3(float v, unsigned short& h,
                                       unsigned short& m, unsigned short& l) {
    h = bfbits(v);       float r  = v - bff(h);
    m = bfbits(r);       float r2 = r - bff(m);
    l = bfbits(r2);
}

// ---- Phase 0: prep — weights transpose, A/B distance K-vectors, out tail ---
// (r8 verbatim) mfma(A,B) = |p|^2 - 2 q.p = surrogate d' in ~f32 accuracy:
//   per dim d: A[6d+..]=[ah,ah,am,ah,al,am], B[6d+..]=[bh,bm,bh,bl,bh,bm]
//   k=18..20: A=[1,1,1], B=split3(|p|^2). k=21..31 zero.
__global__ __launch_bounds__(256) void prep_tail_kernel(
        const float* __restrict__ W1, const float* __restrict__ W2,
        const float* __restrict__ pos, const float* __restrict__ pos_skip,
        __hip_bfloat16* __restrict__ W1t, __hip_bfloat16* __restrict__ W2t,
        __hip_bfloat16* __restrict__ Aq, __hip_bfloat16* __restrict__ Pv,
        float* __restrict__ out, int out_size) {
    const int i = blockIdx.x * 256 + threadIdx.x;
    if (i < PW1) {
        const int k = i / HDIM, n = i % HDIM;
        W1t[n * C_H + k] = __float2bfloat16(W1[i]);
    } else if (i < PW2) {
        const int j = i - PW1;
        const int k = j / HDIM, n = j % HDIM;
        W2t[n * HDIM + k] = __float2bfloat16(W2[j]);
    } else if (i < PPV) {
        const int j = i - PW2;                       // point j -> Pv row
        const float px = pos[j*3+0], py = pos[j*3+1], pz = pos[j*3+2];
        const float pw = px*px + py*py + pz*pz;
        union { unsigned short u[32]; uint4 q[4]; } S;
        #pragma unroll
        for (int k = 0; k < 32; ++k) S.u[k] = 0;
        const float pd[3] = {px, py, pz};
        #pragma unroll
        for (int d = 0; d < 3; ++d) {
            unsigned short bh, bm, bl; split3(pd[d], bh, bm, bl);
            S.u[6*d+0] = bh; S.u[6*d+1] = bm; S.u[6*d+2] = bh;
            S.u[6*d+3] = bl; S.u[6*d+4] = bh; S.u[6*d+5] = bm;
        }
        unsigned short wh, wm, wl; split3(pw, wh, wm, wl);
        S.u[18] = wh; S.u[19] = wm; S.u[20] = wl;
        uint4* dst = (uint4*)(Pv + (size_t)j * 32);
        dst[0] = S.q[0]; dst[1] = S.q[1]; dst[2] = S.q[2]; dst[3] = S.q[3];
    } else if (i < PAQ) {
        const int j = i - PPV;                       // query j -> Aq row
        const float ax = -2.0f * pos_skip[j*3+0];
        const float ay = -2.0f * pos_skip[j*3+1];
        const float az = -2.0f * pos_skip[j*3+2];
        union { unsigned short u[32]; uint4 q[4]; } S;
        #pragma unroll
        for (int k = 0; k < 32; ++k) S.u[k] = 0;
        const float ad[3] = {ax, ay, az};
        #pragma unroll
        for (int d = 0; d < 3; ++d) {
            unsigned short ah, am, al; split3(ad[d], ah, am, al);
            S.u[6*d+0] = ah; S.u[6*d+1] = ah; S.u[6*d+2] = am;
            S.u[6*d+3] = ah; S.u[6*d+4] = al; S.u[6*d+5] = am;
        }
        const unsigned short one = bfbits(1.0f);
        S.u[18] = one; S.u[19] = one; S.u[20] = one;
        uint4* dst = (uint4*)(Aq + (size_t)j * 32);
        dst[0] = S.q[0]; dst[1] = S.q[1]; dst[2] = S.q[2]; dst[3] = S.q[3];
    }
    // output tail: pos_skip passthrough + zero pad
    if (i < M_Q * 3) out[(size_t)M_Q * HDIM + i] = pos_skip[i];
    const int zbase = M_Q * HDIM + M_Q * 3;
    if (zbase + i < out_size) out[zbase + i] = 0.0f;
}

// ---- Mega kernel v8: r8 two-pass MFMA-kNN at 2 independent blocks/CU -------
// QB=32 q/block, 512 thr = 8 waves, grid 512 -> 2 blocks/CU (16 waves/CU).
// Phase pipe overlap is cross-block: block A's gather (VMEM) hides under
// block B's kNN (MFMA/VALU) — no shared barriers between blocks.
// P1: 64 MFMAs/wave (2 q-tiles x 32 p-tiles, C=0) -> values top3 (fmed3),
//     butterfly + wave0 merge -> bb2G[q]. P2: MFMA recompute, capture
//     d' <= bb2G+EPSW. P3: exact f32 rerank (reference d2 + lex tie-break).
// Then gather h[32][392] -> GEMM1 -> hid (overlay) -> GEMM2 -> out.
// LDS 25.4 KB/block; VGPR ~100 (launch_bounds 512,4).
__global__ __launch_bounds__(512, 4) void mega_kernel(
        const __bf16* __restrict__ Aq, const __bf16* __restrict__ Pv,
        const float* __restrict__ pos, const float* __restrict__ pos_skip,
        const float* __restrict__ x, const float* __restrict__ x_skip,
        const __bf16* __restrict__ W1t, const __bf16* __restrict__ W2t,
        const float* __restrict__ b1, const float* __restrict__ b2,
        float* __restrict__ out) {
    __shared__ __align__(16) char smem[25984];
    __hip_bfloat16* h     = (__hip_bfloat16*)smem;            // [32][392] 25.1K (gather..GEMM1)
    __hip_bfloat16* hid   = (__hip_bfloat16*)smem;            // [32][264] overlays h post-GEMM1
    float*          candD = (float*)smem;                     // [8][32][3] 3K (P1/merge)
    int*            candI = (int*)  (smem + 3072);            // [32][24]  3K (P2/P3)
    int*            candC = (int*)  (smem + 6144);            // [32]
    float*          bb2G  = (float*)(smem + 25088);           // [32]
    int*            idxL  = (int*)  (smem + 25216);           // [96]
    float*          wnL   = (float*)(smem + 25600);           // [96]

    const int t    = threadIdx.x;
    const int m0   = blockIdx.x * QB;
    const int wave = t >> 6, lane = t & 63;
    const int ln = lane & 15, kq = lane >> 4;

    if (t < 32) candC[t] = 0;

    // x_skip preload (consumed in gather phase): 32 rows x 32 f4 = 1024, 2/thr
    float4 skipv[2];
    #pragma unroll
    for (int p = 0; p < 2; ++p) {
        const int g = p * 512 + t;
        const int r = g >> 5, c = (g & 31) * 4;
        skipv[p] = *(const float4*)(x_skip + (size_t)(m0 + r) * C_SKIP + c);
    }

    // resident A-frags: 2 q-tiles x 8 bf16
    bf16x8 afq[2];
    #pragma unroll
    for (int qt = 0; qt < 2; ++qt)
        afq[qt] = *(const bf16x8*)(Aq + (size_t)(m0 + qt*16 + ln) * 32 + kq*8);

    const f32x4 zacc = {0.0f, 0.0f, 0.0f, 0.0f};
    const int ptbase = wave * 32;                  // wave owns 32 p-tiles = 512 pts

    // ---- Phase 1: MFMA distances, values-only top3 ----
    float b0_[2][4], b1_[2][4], b2_[2][4];
    #pragma unroll
    for (int qt = 0; qt < 2; ++qt)
        #pragma unroll
        for (int r = 0; r < 4; ++r) { b0_[qt][r]=3e38f; b1_[qt][r]=3e38f; b2_[qt][r]=3e38f; }

    bf16x8 bcur = *(const bf16x8*)(Pv + (size_t)(ptbase*16 + ln) * 32 + kq*8);
    for (int pt = 0; pt < 32; ++pt) {
        bf16x8 bnext;
        if (pt < 31)
            bnext = *(const bf16x8*)(Pv + (size_t)((ptbase+pt+1)*16 + ln) * 32 + kq*8);
        #pragma unroll
        for (int qt = 0; qt < 2; ++qt) {
            const f32x4 d = __builtin_amdgcn_mfma_f32_16x16x32_bf16(afq[qt], bcur, zacc, 0,0,0);
            #pragma unroll
            for (int r = 0; r < 4; ++r) {
                b2_[qt][r] = __builtin_amdgcn_fmed3f(d[r], b1_[qt][r], b2_[qt][r]);
                b1_[qt][r] = __builtin_amdgcn_fmed3f(d[r], b0_[qt][r], b1_[qt][r]);
                b0_[qt][r] = fminf(b0_[qt][r], d[r]);
            }
        }
        bcur = bnext;
    }
    // butterfly merge across the 16 lanes (ln) sharing each row-group
    #pragma unroll
    for (int qt = 0; qt < 2; ++qt)
        #pragma unroll
        for (int r = 0; r < 4; ++r) {
            float v0 = b0_[qt][r], v1 = b1_[qt][r], v2 = b2_[qt][r];
            #pragma unroll
            for (int m = 1; m <= 8; m <<= 1) {
                const float o0 = __shfl_xor(v0, m), o1 = __shfl_xor(v1, m), o2 = __shfl_xor(v2, m);
                const float mx  = fmaxf(v0, o0);
                const float z0  = fminf(v0, o0);
                const float mn1 = fminf(v1, o1);
                const float mn2 = fminf(v2, o2);
                v0 = z0;
                v1 = fminf(mx, mn1);
                v2 = __builtin_amdgcn_fmed3f(mx, mn1, mn2);
            }
            b0_[qt][r] = v0; b1_[qt][r] = v1; b2_[qt][r] = v2;
        }
    if (ln == 0) {
        #pragma unroll
        for (int qt = 0; qt < 2; ++qt)
            #pragma unroll
            for (int r = 0; r < 4; ++r) {
                const int base = (wave*32 + qt*16 + kq*4 + r) * 3;
                candD[base+0] = b0_[qt][r];
                candD[base+1] = b1_[qt][r];
                candD[base+2] = b2_[qt][r];
            }
    }
    __syncthreads();

    // ---- wave0: merge 8 wave-triples -> bb2G (3rd-best approx value) ----
    if (t < 32) {
        float B0 = 3e38f, B1 = 3e38f, B2 = 3e38f;
        #pragma unroll
        for (int ww = 0; ww < 8; ++ww) {
            const int base = (ww*32 + t) * 3;
            #pragma unroll
            for (int k = 0; k < 3; ++k) {
                const float v = candD[base+k];
                B2 = __builtin_amdgcn_fmed3f(v, B1, B2);
                B1 = __builtin_amdgcn_fmed3f(v, B0, B1);
                B0 = fminf(B0, v);
            }
        }
        bb2G[t] = B2;
    }
    __syncthreads();

    // ---- Phase 2: recompute + capture candidates within window ----
    float thr[2][4];
    #pragma unroll
    for (int qt = 0; qt < 2; ++qt)
        #pragma unroll
        for (int r = 0; r < 4; ++r)
            thr[qt][r] = bb2G[qt*16 + kq*4 + r] + EPSW;

    bcur = *(const bf16x8*)(Pv + (size_t)(ptbase*16 + ln) * 32 + kq*8);
    for (int pt = 0; pt < 32; ++pt) {
        bf16x8 bnext;
        if (pt < 31)
            bnext = *(const bf16x8*)(Pv + (size_t)((ptbase+pt+1)*16 + ln) * 32 + kq*8);
        const int pidx = (ptbase + pt) * 16 + ln;
        #pragma unroll
        for (int qt = 0; qt < 2; ++qt) {
            const f32x4 d = __builtin_amdgcn_mfma_f32_16x16x32_bf16(afq[qt], bcur, zacc, 0,0,0);
            const bool h0 = d[0] <= thr[qt][0], h1 = d[1] <= thr[qt][1];
            const bool h2 = d[2] <= thr[qt][2], h3 = d[3] <= thr[qt][3];
            if (__builtin_expect(h0|h1|h2|h3, 0)) {
                #pragma unroll
                for (int r = 0; r < 4; ++r) {
                    if (d[r] <= thr[qt][r]) {
                        const int row = qt*16 + kq*4 + r;
                        const int n = atomicAdd(&candC[row], 1);
                        if (n < CANDMAX) candI[row*CANDMAX + n] = pidx;
                    }
                }
            }
        }
        bcur = bnext;
    }
    __syncthreads();

    // ---- Phase 3: exact f32 select on candidates (lane = query) ----
    if (t < 32) {
        const int q = m0 + t;
        const float qx = pos_skip[q*3+0], qy = pos_skip[q*3+1], qz = pos_skip[q*3+2];
        int cnt = candC[t]; if (cnt > CANDMAX) cnt = CANDMAX;
        float e0 = 3e38f, e1 = 3e38f, e2 = 3e38f;
        int   i0 = 0x7fffffff, i1 = 0x7fffffff, i2 = 0x7fffffff;
        for (int c = 0; c < cnt; ++c) {
            const int j = candI[t*CANDMAX + c];
            const float dx = qx - pos[j*3+0];
            const float dy = qy - pos[j*3+1];
            const float dz = qz - pos[j*3+2];
            const float d2 = dx*dx + dy*dy + dz*dz;    // exact reference d2k
            // lexicographic (d2, idx) insert -> reference tie-break (lowest idx)
            const bool c2 = (d2 < e2) || (d2 == e2 && j < i2);
            if (c2) {
                const bool c1 = (d2 < e1) || (d2 == e1 && j < i1);
                if (c1) {
                    e2 = e1; i2 = i1;
                    const bool c0 = (d2 < e0) || (d2 == e0 && j < i0);
                    if (c0) { e1 = e0; i1 = i0; e0 = d2; i0 = j; }
                    else    { e1 = d2; i1 = j; }
                } else { e2 = d2; i2 = j; }
            }
        }
        const float w0 = 1.0f / fmaxf(e0, 1e-16f);
        const float w1 = 1.0f / fmaxf(e1, 1e-16f);
        const float w2 = 1.0f / fmaxf(e2, 1e-16f);
        const float inv = 1.0f / (w0 + w1 + w2);
        idxL[t*3+0] = i0; idxL[t*3+1] = i1; idxL[t*3+2] = i2;
        wnL[t*3+0] = w0*inv; wnL[t*3+1] = w1*inv; wnL[t*3+2] = w2*inv;
    }
    __syncthreads();   // cand region dead; h arena free

    const int wm  = (wave >> 2) * 16;   // 2 m-wave-rows of 16
    const int wnc = (wave & 3) * 64;    // 4 n-wave-cols of 64

    // ---- weight frag prefetch (k=0,32): in flight during gather ----
    bf16x8 bfA[4], bfB[4];
    #pragma unroll
    for (int nt = 0; nt < 4; ++nt) {
        bfA[nt] = *(const bf16x8*)(W1t + (size_t)(wnc + nt*16 + ln) * C_H +  0 + kq*8);
        bfB[nt] = *(const bf16x8*)(W1t + (size_t)(wnc + nt*16 + ln) * C_H + 32 + kq*8);
    }

    // ---- gather-interp + skip concat into h ----
    #pragma unroll
    for (int p = 0; p < 2; ++p) {
        const int g = p * 512 + t;
        const int r = g >> 5, c = (g & 31) * 4;
        union { __hip_bfloat162 v2[2]; uint2 u; } pk;
        pk.v2[0].x = __float2bfloat16(skipv[p].x); pk.v2[0].y = __float2bfloat16(skipv[p].y);
        pk.v2[1].x = __float2bfloat16(skipv[p].z); pk.v2[1].y = __float2bfloat16(skipv[p].w);
        *(uint2*)&h[(size_t)r * 392 + C_IN + c] = pk.u;
    }
    #pragma unroll 4
    for (int p = 0; p < 4; ++p) {
        const int g = p * 512 + t;                 // 0..2047
        const int r = g >> 6, c = (g & 63) * 4;
        const int   i0 = idxL[r*3+0], i1 = idxL[r*3+1], i2 = idxL[r*3+2];
        const float w0 = wnL[r*3+0],  w1 = wnL[r*3+1],  w2 = wnL[r*3+2];
        const float4 v0 = *(const float4*)(x + (size_t)i0 * C_IN + c);
        const float4 v1 = *(const float4*)(x + (size_t)i1 * C_IN + c);
        const float4 v2 = *(const float4*)(x + (size_t)i2 * C_IN + c);
        union { __hip_bfloat162 v2_[2]; uint2 u; } pk;
        pk.v2_[0].x = __float2bfloat16(w0*v0.x + w1*v1.x + w2*v2.x);
        pk.v2_[0].y = __float2bfloat16(w0*v0.y + w1*v1.y + w2*v2.y);
        pk.v2_[1].x = __float2bfloat16(w0*v0.z + w1*v1.z + w2*v2.z);
        pk.v2_[1].y = __float2bfloat16(w0*v0.w + w1*v1.w + w2*v2.w);
        *(uint2*)&h[(size_t)r * 392 + c] = pk.u;
    }
    __syncthreads();   // h complete

    f32x4 acc[4] = {};

    // ---- stage 1: hid = relu(h @ W1t^T + b1), K=384, barrier-free ----
    #pragma unroll
    for (int s = 0; s < 12; ++s) {
        const int k0 = s * 32;
        bf16x8* bc = (s & 1) ? bfB : bfA;
        const bf16x8 a0 = *(const bf16x8*)&h[(size_t)(wm + ln) * 392 + k0 + kq*8];
        #pragma unroll
        for (int nt = 0; nt < 4; ++nt)
            acc[nt] = __builtin_amdgcn_mfma_f32_16x16x32_bf16(a0, bc[nt], acc[nt], 0,0,0);
        if (s < 10) {
            #pragma unroll
            for (int nt = 0; nt < 4; ++nt)
                bc[nt] = *(const bf16x8*)(W1t + (size_t)(wnc + nt*16 + ln) * C_H + (k0 + 64) + kq*8);
        } else {
            #pragma unroll
            for (int nt = 0; nt < 4; ++nt)
                bc[nt] = *(const bf16x8*)(W2t + (size_t)(wnc + nt*16 + ln) * HDIM + (s - 10) * 32 + kq*8);
        }
    }
    __syncthreads();   // all h reads done -> arena reusable as hid

    // stage-1 epilogue: bias + relu -> hid (overlays h), reset acc
    #pragma unroll
    for (int nt = 0; nt < 4; ++nt) {
        const int n = wnc + nt*16 + ln;
        const float bv = b1[n];
        const int rbase = wm + kq*4;
        #pragma unroll
        for (int r = 0; r < 4; ++r) {
            const float v = fmaxf(acc[nt][r] + bv, 0.0f);
            hid[(size_t)(rbase + r) * 264 + n] = __float2bfloat16(v);
            acc[nt][r] = 0.0f;
        }
    }
    __syncthreads();

    // ---- stage 2: out = hid @ W2t^T + b2, K=256, barrier-free ----
    #pragma unroll
    for (int s = 0; s < 8; ++s) {
        const int k0 = s * 32;
        bf16x8* bc = (s & 1) ? bfB : bfA;          // parity continues from stage 1
        const bf16x8 a0 = *(const bf16x8*)&hid[(size_t)(wm + ln) * 264 + k0 + kq*8];
        #pragma unroll
        for (int nt = 0; nt < 4; ++nt)
            acc[nt] = __builtin_amdgcn_mfma_f32_16x16x32_bf16(a0, bc[nt], acc[nt], 0,0,0);
        if (s < 6) {
            #pragma unroll
            for (int nt = 0; nt < 4; ++nt)
                bc[nt] = *(const bf16x8*)(W2t + (size_t)(wnc + nt*16 + ln) * HDIM + (k0 + 64) + kq*8);
        }
    }

    // stage-2 epilogue: bias -> out (fp32)
    #pragma unroll
    for (int nt = 0; nt < 4; ++nt) {
        const int n = wnc + nt*16 + ln;
        const float bv = b2[n];
        const int rbase = m0 + wm + kq*4;
        #pragma unroll
        for (int r = 0; r < 4; ++r)
            out[(size_t)(rbase + r) * HDIM + n] = acc[nt][r] + bv;
    }
}

extern "C" void kernel_launch(void* const* d_in, const int* in_sizes, int n_in,
                              void* d_out, int out_size, void* d_ws, size_t ws_size,
                              hipStream_t stream) {
    (void)in_sizes; (void)n_in; (void)ws_size;
    const float* x        = (const float*)d_in[0];   // [4096,256]
    const float* pos      = (const float*)d_in[1];   // [4096,3]
    const float* x_skip   = (const float*)d_in[3];   // [16384,128]
    const float* pos_skip = (const float*)d_in[4];   // [16384,3]
    const float* W1       = (const float*)d_in[6];   // [384,256]
    const float* b1       = (const float*)d_in[7];   // [256]
    const float* W2       = (const float*)d_in[8];   // [256,256]
    const float* b2       = (const float*)d_in[9];   // [256]
    float* out = (float*)d_out;

    char* ws = (char*)d_ws;
    __hip_bfloat16* W1t = (__hip_bfloat16*)(ws);             //   196,608
    __hip_bfloat16* W2t = (__hip_bfloat16*)(ws + 196608);    //   131,072
    __hip_bfloat16* Aq  = (__hip_bfloat16*)(ws + 327680);    // 1,048,576 (16384 x 32 bf16)
    __hip_bfloat16* Pv  = (__hip_bfloat16*)(ws + 1376256);   //   262,144 ( 4096 x 32 bf16)
                                                             // total ~1.64 MB

    prep_tail_kernel<<<(PAQ + 255)/256, 256, 0, stream>>>(
        W1, W2, pos, pos_skip, W1t, W2t, Aq, Pv, out, out_size);
    mega_kernel<<<M_Q/QB, 512, 0, stream>>>(
        (const __bf16*)Aq, (const __bf16*)Pv, pos, pos_skip, x, x_skip,
        (const __bf16*)W1t, (const __bf16*)W2t, b1, b2, out);
}

// Round 12
// 145.284 us; speedup vs baseline: 1.0342x; 1.0342x over previous
//
#include <hip/hip_runtime.h>
#include <hip/hip_bf16.h>

#define N_PTS  4096
#define M_Q    16384
#define C_IN   256
#define C_SKIP 128
#define C_H    384      // C_IN + C_SKIP
#define HDIM   256
#define QB     64       // queries per block -> 256 blocks = 1/CU
#define CANDMAX 24
#define EPSW   4e-3f    // capture window >= 2x worst-case MFMA d' error (~4e-4)

typedef __bf16 bf16x8 __attribute__((ext_vector_type(8)));
typedef float  f32x4  __attribute__((ext_vector_type(4)));

// prep segment boundaries
#define PW1  (C_H*HDIM)                    //  98304
#define PW2  (PW1 + HDIM*HDIM)             // 163840
#define PPV  (PW2 + N_PTS)                 // 167936
#define PAQ  (PPV + M_Q)                   // 184320

__device__ __forceinline__ unsigned short bfbits(float v) {
    __hip_bfloat16 b = __float2bfloat16(v);
    return *(unsigned short*)&b;
}
__device__ __forceinline__ float bff(unsigned short u) {
    __hip_bfloat16 b = *(__hip_bfloat16*)&u;
    return __bfloat162float(b);
}
// 3-way bf16 split: v = h + m + l + O(2^-27 v)
__device__ __forceinline__ void split3(float v, unsigned short& h,
                                       unsigned short& m, unsigned short& l) {
    h = bfbits(v);       float r  = v - bff(h);
    m = bfbits(r);       float r2 = r - bff(m);
    l = bfbits(r2);
}

// ---- Phase 0: prep — weights transpose, A/B distance K-vectors, out tail ---
// (r8 verbatim) mfma(A,B) = |p|^2 - 2 q.p = surrogate d' in ~f32 accuracy:
//   per dim d: A[6d+..]=[ah,ah,am,ah,al,am], B[6d+..]=[bh,bm,bh,bl,bh,bm]
//   k=18..20: A=[1,1,1], B=split3(|p|^2). k=21..31 zero.
__global__ __launch_bounds__(256) void prep_tail_kernel(
        const float* __restrict__ W1, const float* __restrict__ W2,
        const float* __restrict__ pos, const float* __restrict__ pos_skip,
        __hip_bfloat16* __restrict__ W1t, __hip_bfloat16* __restrict__ W2t,
        __hip_bfloat16* __restrict__ Aq, __hip_bfloat16* __restrict__ Pv,
        float* __restrict__ out, int out_size) {
    const int i = blockIdx.x * 256 + threadIdx.x;
    if (i < PW1) {
        const int k = i / HDIM, n = i % HDIM;
        W1t[n * C_H + k] = __float2bfloat16(W1[i]);
    } else if (i < PW2) {
        const int j = i - PW1;
        const int k = j / HDIM, n = j % HDIM;
        W2t[n * HDIM + k] = __float2bfloat16(W2[j]);
    } else if (i < PPV) {
        const int j = i - PW2;                       // point j -> Pv row
        const float px = pos[j*3+0], py = pos[j*3+1], pz = pos[j*3+2];
        const float pw = px*px + py*py + pz*pz;
        union { unsigned short u[32]; uint4 q[4]; } S;
        #pragma unroll
        for (int k = 0; k < 32; ++k) S.u[k] = 0;
        const float pd[3] = {px, py, pz};
        #pragma unroll
        for (int d = 0; d < 3; ++d) {
            unsigned short bh, bm, bl; split3(pd[d], bh, bm, bl);
            S.u[6*d+0] = bh; S.u[6*d+1] = bm; S.u[6*d+2] = bh;
            S.u[6*d+3] = bl; S.u[6*d+4] = bh; S.u[6*d+5] = bm;
        }
        unsigned short wh, wm, wl; split3(pw, wh, wm, wl);
        S.u[18] = wh; S.u[19] = wm; S.u[20] = wl;
        uint4* dst = (uint4*)(Pv + (size_t)j * 32);
        dst[0] = S.q[0]; dst[1] = S.q[1]; dst[2] = S.q[2]; dst[3] = S.q[3];
    } else if (i < PAQ) {
        const int j = i - PPV;                       // query j -> Aq row
        const float ax = -2.0f * pos_skip[j*3+0];
        const float ay = -2.0f * pos_skip[j*3+1];
        const float az = -2.0f * pos_skip[j*3+2];
        union { unsigned short u[32]; uint4 q[4]; } S;
        #pragma unroll
        for (int k = 0; k < 32; ++k) S.u[k] = 0;
        const float ad[3] = {ax, ay, az};
        #pragma unroll
        for (int d = 0; d < 3; ++d) {
            unsigned short ah, am, al; split3(ad[d], ah, am, al);
            S.u[6*d+0] = ah; S.u[6*d+1] = ah; S.u[6*d+2] = am;
            S.u[6*d+3] = ah; S.u[6*d+4] = al; S.u[6*d+5] = am;
        }
        const unsigned short one = bfbits(1.0f);
        S.u[18] = one; S.u[19] = one; S.u[20] = one;
        uint4* dst = (uint4*)(Aq + (size_t)j * 32);
        dst[0] = S.q[0]; dst[1] = S.q[1]; dst[2] = S.q[2]; dst[3] = S.q[3];
    }
    // output tail: pos_skip passthrough + zero pad
    if (i < M_Q * 3) out[(size_t)M_Q * HDIM + i] = pos_skip[i];
    const int zbase = M_Q * HDIM + M_Q * 3;
    if (zbase + i < out_size) out[zbase + i] = 0.0f;
}

// ---- Mega kernel v9: r8 structure + latency-hiding fixes -------------------
// 64 q/block, 512 thr = 8 waves, grid 256 = 1 block/CU (measured-best r8).
// Changes vs r8 (each targets exposed latency, not issue count):
//  (1) Pv stream prefetch depth 2 in P1 and P2 (L2 ~225cyc > 1-iter work)
//  (2) x_skip preload issued AFTER P1 (vmcnt is issue-ordered: cold x_skip
//      loads ahead of Pv blocked the first P1 waits); merge+P3 hides it
//  (3) GEMM A-fragment (ds_read) one-step-ahead register double-buffer
__global__ __launch_bounds__(512) void mega_kernel(
        const __bf16* __restrict__ Aq, const __bf16* __restrict__ Pv,
        const float* __restrict__ pos, const float* __restrict__ pos_skip,
        const float* __restrict__ x, const float* __restrict__ x_skip,
        const __bf16* __restrict__ W1t, const __bf16* __restrict__ W2t,
        const float* __restrict__ b1, const float* __restrict__ b2,
        float* __restrict__ out) {
    __shared__ __align__(16) char smem[51968];
    __hip_bfloat16* h     = (__hip_bfloat16*)smem;            // [64][392] 50.2K (gather..GEMM1)
    __hip_bfloat16* hid   = (__hip_bfloat16*)smem;            // [64][264] overlays h post-GEMM1
    float*          candD = (float*)smem;                     // [8][64][3] 6K   (P1/merge)
    int*            candI = (int*)  (smem + 6144);            // [64][24]  6K   (P2/P3)
    int*            candC = (int*)  (smem + 12288);           // [64]      256B
    float*          bb2G  = (float*)(smem + 50176);           // [64]
    int*            idxL  = (int*)  (smem + 50432);           // [192]
    float*          wnL   = (float*)(smem + 51200);           // [192]

    const int t    = threadIdx.x;
    const int m0   = blockIdx.x * QB;
    const int wave = t >> 6, lane = t & 63;
    const int ln = lane & 15, kq = lane >> 4;

    if (t < 64) candC[t] = 0;

    const int ptbase = wave * 32;                  // p-tile base (16 pts each)

    // ---- Pv depth-2 prefetch + resident A-frags FIRST (no older VMEM) ----
    bf16x8 bcur = *(const bf16x8*)(Pv + (size_t)(ptbase*16 + ln) * 32 + kq*8);
    bf16x8 bn1  = *(const bf16x8*)(Pv + (size_t)((ptbase+1)*16 + ln) * 32 + kq*8);
    bf16x8 afq[4];
    #pragma unroll
    for (int qt = 0; qt < 4; ++qt)
        afq[qt] = *(const bf16x8*)(Aq + (size_t)(m0 + qt*16 + ln) * 32 + kq*8);

    const f32x4 zacc = {0.0f, 0.0f, 0.0f, 0.0f};

    // ---- Phase 1: MFMA distances, values-only top3 (Pv depth-2) ----
    float b0_[4][4], b1_[4][4], b2_[4][4];
    #pragma unroll
    for (int qt = 0; qt < 4; ++qt)
        #pragma unroll
        for (int r = 0; r < 4; ++r) { b0_[qt][r]=3e38f; b1_[qt][r]=3e38f; b2_[qt][r]=3e38f; }

    for (int pt = 0; pt < 32; ++pt) {
        bf16x8 bn2;
        if (pt < 30)
            bn2 = *(const bf16x8*)(Pv + (size_t)((ptbase+pt+2)*16 + ln) * 32 + kq*8);
        #pragma unroll
        for (int qt = 0; qt < 4; ++qt) {
            const f32x4 d = __builtin_amdgcn_mfma_f32_16x16x32_bf16(afq[qt], bcur, zacc, 0,0,0);
            #pragma unroll
            for (int r = 0; r < 4; ++r) {
                b2_[qt][r] = __builtin_amdgcn_fmed3f(d[r], b1_[qt][r], b2_[qt][r]);
                b1_[qt][r] = __builtin_amdgcn_fmed3f(d[r], b0_[qt][r], b1_[qt][r]);
                b0_[qt][r] = fminf(b0_[qt][r], d[r]);
            }
        }
        bcur = bn1; bn1 = bn2;
    }
    // butterfly merge across the 16 lanes (ln) sharing each row-group
    #pragma unroll
    for (int qt = 0; qt < 4; ++qt)
        #pragma unroll
        for (int r = 0; r < 4; ++r) {
            float v0 = b0_[qt][r], v1 = b1_[qt][r], v2 = b2_[qt][r];
            #pragma unroll
            for (int m = 1; m <= 8; m <<= 1) {
                const float o0 = __shfl_xor(v0, m), o1 = __shfl_xor(v1, m), o2 = __shfl_xor(v2, m);
                const float mx  = fmaxf(v0, o0);
                const float z0  = fminf(v0, o0);
                const float mn1 = fminf(v1, o1);
                const float mn2 = fminf(v2, o2);
                v0 = z0;
                v1 = fminf(mx, mn1);
                v2 = __builtin_amdgcn_fmed3f(mx, mn1, mn2);
            }
            b0_[qt][r] = v0; b1_[qt][r] = v1; b2_[qt][r] = v2;
        }
    if (ln == 0) {
        #pragma unroll
        for (int qt = 0; qt < 4; ++qt)
            #pragma unroll
            for (int r = 0; r < 4; ++r) {
                const int base = (wave*64 + qt*16 + kq*4 + r) * 3;
                candD[base+0] = b0_[qt][r];
                candD[base+1] = b1_[qt][r];
                candD[base+2] = b2_[qt][r];
            }
    }

    // ---- x_skip preload issued HERE (after all P1 Pv waits) ----
    float4 skipv[4];
    #pragma unroll
    for (int p = 0; p < 4; ++p) {
        const int g = p * 512 + t;
        const int r = g >> 5, c = (g & 31) * 4;
        skipv[p] = *(const float4*)(x_skip + (size_t)(m0 + r) * C_SKIP + c);
    }
    __syncthreads();

    // ---- wave0: merge 8 wave-triples -> bb2G (3rd-best approx value) ----
    if (t < 64) {
        float B0 = 3e38f, B1 = 3e38f, B2 = 3e38f;
        #pragma unroll
        for (int ww = 0; ww < 8; ++ww) {
            const int base = (ww*64 + t) * 3;
            #pragma unroll
            for (int k = 0; k < 3; ++k) {
                const float v = candD[base+k];
                B2 = __builtin_amdgcn_fmed3f(v, B1, B2);
                B1 = __builtin_amdgcn_fmed3f(v, B0, B1);
                B0 = fminf(B0, v);
            }
        }
        bb2G[t] = B2;
    }
    __syncthreads();

    // ---- Phase 2: recompute + capture candidates within window (depth-2) ----
    float thr[4][4];
    #pragma unroll
    for (int qt = 0; qt < 4; ++qt)
        #pragma unroll
        for (int r = 0; r < 4; ++r)
            thr[qt][r] = bb2G[qt*16 + kq*4 + r] + EPSW;

    bcur = *(const bf16x8*)(Pv + (size_t)(ptbase*16 + ln) * 32 + kq*8);
    bn1  = *(const bf16x8*)(Pv + (size_t)((ptbase+1)*16 + ln) * 32 + kq*8);
    for (int pt = 0; pt < 32; ++pt) {
        bf16x8 bn2;
        if (pt < 30)
            bn2 = *(const bf16x8*)(Pv + (size_t)((ptbase+pt+2)*16 + ln) * 32 + kq*8);
        const int pidx = (ptbase + pt) * 16 + ln;
        #pragma unroll
        for (int qt = 0; qt < 4; ++qt) {
            const f32x4 d = __builtin_amdgcn_mfma_f32_16x16x32_bf16(afq[qt], bcur, zacc, 0,0,0);
            const bool h0 = d[0] <= thr[qt][0], h1 = d[1] <= thr[qt][1];
            const bool h2 = d[2] <= thr[qt][2], h3 = d[3] <= thr[qt][3];
            if (__builtin_expect(h0|h1|h2|h3, 0)) {
                #pragma unroll
                for (int r = 0; r < 4; ++r) {
                    if (d[r] <= thr[qt][r]) {
                        const int row = qt*16 + kq*4 + r;
                        const int n = atomicAdd(&candC[row], 1);
                        if (n < CANDMAX) candI[row*CANDMAX + n] = pidx;
                    }
                }
            }
        }
        bcur = bn1; bn1 = bn2;
    }
    __syncthreads();

    // ---- Phase 3: exact f32 select on candidates (wave0, lane = query) ----
    if (t < 64) {
        const int q = m0 + t;
        const float qx = pos_skip[q*3+0], qy = pos_skip[q*3+1], qz = pos_skip[q*3+2];
        int cnt = candC[t]; if (cnt > CANDMAX) cnt = CANDMAX;
        float e0 = 3e38f, e1 = 3e38f, e2 = 3e38f;
        int   i0 = 0x7fffffff, i1 = 0x7fffffff, i2 = 0x7fffffff;
        for (int c = 0; c < cnt; ++c) {
            const int j = candI[t*CANDMAX + c];
            const float dx = qx - pos[j*3+0];
            const float dy = qy - pos[j*3+1];
            const float dz = qz - pos[j*3+2];
            const float d2 = dx*dx + dy*dy + dz*dz;    // exact reference d2k
            // lexicographic (d2, idx) insert -> reference tie-break (lowest idx)
            const bool c2 = (d2 < e2) || (d2 == e2 && j < i2);
            if (c2) {
                const bool c1 = (d2 < e1) || (d2 == e1 && j < i1);
                if (c1) {
                    e2 = e1; i2 = i1;
                    const bool c0 = (d2 < e0) || (d2 == e0 && j < i0);
                    if (c0) { e1 = e0; i1 = i0; e0 = d2; i0 = j; }
                    else    { e1 = d2; i1 = j; }
                } else { e2 = d2; i2 = j; }
            }
        }
        const float w0 = 1.0f / fmaxf(e0, 1e-16f);
        const float w1 = 1.0f / fmaxf(e1, 1e-16f);
        const float w2 = 1.0f / fmaxf(e2, 1e-16f);
        const float inv = 1.0f / (w0 + w1 + w2);
        idxL[t*3+0] = i0; idxL[t*3+1] = i1; idxL[t*3+2] = i2;
        wnL[t*3+0] = w0*inv; wnL[t*3+1] = w1*inv; wnL[t*3+2] = w2*inv;
    }
    __syncthreads();   // cand region dead; h arena free

    const int wm  = (wave >> 2) * 32;   // 2 m-wave-rows of 32
    const int wnc = (wave & 3) * 64;    // 4 n-wave-cols of 64

    // ---- weight frag prefetch (k=0,32): in flight during gather ----
    bf16x8 bfA[4], bfB[4];
    #pragma unroll
    for (int nt = 0; nt < 4; ++nt) {
        bfA[nt] = *(const bf16x8*)(W1t + (size_t)(wnc + nt*16 + ln) * C_H +  0 + kq*8);
        bfB[nt] = *(const bf16x8*)(W1t + (size_t)(wnc + nt*16 + ln) * C_H + 32 + kq*8);
    }

    // ---- gather-interp + skip concat into h ----
    #pragma unroll
    for (int p = 0; p < 4; ++p) {
        const int g = p * 512 + t;
        const int r = g >> 5, c = (g & 31) * 4;
        union { __hip_bfloat162 v2[2]; uint2 u; } pk;
        pk.v2[0].x = __float2bfloat16(skipv[p].x); pk.v2[0].y = __float2bfloat16(skipv[p].y);
        pk.v2[1].x = __float2bfloat16(skipv[p].z); pk.v2[1].y = __float2bfloat16(skipv[p].w);
        *(uint2*)&h[(size_t)r * 392 + C_IN + c] = pk.u;
    }
    #pragma unroll 4
    for (int p = 0; p < 8; ++p) {
        const int g = p * 512 + t;                 // 0..4095
        const int r = g >> 6, c = (g & 63) * 4;
        const int   i0 = idxL[r*3+0], i1 = idxL[r*3+1], i2 = idxL[r*3+2];
        const float w0 = wnL[r*3+0],  w1 = wnL[r*3+1],  w2 = wnL[r*3+2];
        const float4 v0 = *(const float4*)(x + (size_t)i0 * C_IN + c);
        const float4 v1 = *(const float4*)(x + (size_t)i1 * C_IN + c);
        const float4 v2 = *(const float4*)(x + (size_t)i2 * C_IN + c);
        union { __hip_bfloat162 v2_[2]; uint2 u; } pk;
        pk.v2_[0].x = __float2bfloat16(w0*v0.x + w1*v1.x + w2*v2.x);
        pk.v2_[0].y = __float2bfloat16(w0*v0.y + w1*v1.y + w2*v2.y);
        pk.v2_[1].x = __float2bfloat16(w0*v0.z + w1*v1.z + w2*v2.z);
        pk.v2_[1].y = __float2bfloat16(w0*v0.w + w1*v1.w + w2*v2.w);
        *(uint2*)&h[(size_t)r * 392 + c] = pk.u;
    }
    __syncthreads();   // h complete

    f32x4 acc[2][4] = {};

    // ---- stage 1: hid = relu(h @ W1t^T + b1), K=384, A-frag double-buffer ----
    bf16x8 a0c = *(const bf16x8*)&h[(size_t)(wm +      ln) * 392 + kq*8];
    bf16x8 a1c = *(const bf16x8*)&h[(size_t)(wm + 16 + ln) * 392 + kq*8];
    #pragma unroll
    for (int s = 0; s < 12; ++s) {
        const int k0 = s * 32;
        bf16x8 a0n, a1n;
        if (s < 11) {
            a0n = *(const bf16x8*)&h[(size_t)(wm +      ln) * 392 + k0 + 32 + kq*8];
            a1n = *(const bf16x8*)&h[(size_t)(wm + 16 + ln) * 392 + k0 + 32 + kq*8];
        }
        bf16x8* bc = (s & 1) ? bfB : bfA;
        #pragma unroll
        for (int nt = 0; nt < 4; ++nt)
            acc[0][nt] = __builtin_amdgcn_mfma_f32_16x16x32_bf16(a0c, bc[nt], acc[0][nt], 0,0,0);
        #pragma unroll
        for (int nt = 0; nt < 4; ++nt)
            acc[1][nt] = __builtin_amdgcn_mfma_f32_16x16x32_bf16(a1c, bc[nt], acc[1][nt], 0,0,0);
        if (s < 10) {
            #pragma unroll
            for (int nt = 0; nt < 4; ++nt)
                bc[nt] = *(const bf16x8*)(W1t + (size_t)(wnc + nt*16 + ln) * C_H + (k0 + 64) + kq*8);
        } else {
            #pragma unroll
            for (int nt = 0; nt < 4; ++nt)
                bc[nt] = *(const bf16x8*)(W2t + (size_t)(wnc + nt*16 + ln) * HDIM + (s - 10) * 32 + kq*8);
        }
        a0c = a0n; a1c = a1n;
    }
    __syncthreads();   // all h reads done -> arena reusable as hid

    // stage-1 epilogue: bias + relu -> hid (overlays h), reset acc
    #pragma unroll
    for (int nt = 0; nt < 4; ++nt) {
        const int n = wnc + nt*16 + ln;
        const float bv = b1[n];
        #pragma unroll
        for (int mt = 0; mt < 2; ++mt) {
            const int rbase = wm + mt*16 + kq*4;
            #pragma unroll
            for (int r = 0; r < 4; ++r) {
                const float v = fmaxf(acc[mt][nt][r] + bv, 0.0f);
                hid[(size_t)(rbase + r) * 264 + n] = __float2bfloat16(v);
                acc[mt][nt][r] = 0.0f;
            }
        }
    }
    __syncthreads();

    // ---- stage 2: out = hid @ W2t^T + b2, K=256, A-frag double-buffer ----
    a0c = *(const bf16x8*)&hid[(size_t)(wm +      ln) * 264 + kq*8];
    a1c = *(const bf16x8*)&hid[(size_t)(wm + 16 + ln) * 264 + kq*8];
    #pragma unroll
    for (int s = 0; s < 8; ++s) {
        const int k0 = s * 32;
        bf16x8 a0n, a1n;
        if (s < 7) {
            a0n = *(const bf16x8*)&hid[(size_t)(wm +      ln) * 264 + k0 + 32 + kq*8];
            a1n = *(const bf16x8*)&hid[(size_t)(wm + 16 + ln) * 264 + k0 + 32 + kq*8];
        }
        bf16x8* bc = (s & 1) ? bfB : bfA;          // parity continues from stage 1
        #pragma unroll
        for (int nt = 0; nt < 4; ++nt)
            acc[0][nt] = __builtin_amdgcn_mfma_f32_16x16x32_bf16(a0c, bc[nt], acc[0][nt], 0,0,0);
        #pragma unroll
        for (int nt = 0; nt < 4; ++nt)
            acc[1][nt] = __builtin_amdgcn_mfma_f32_16x16x32_bf16(a1c, bc[nt], acc[1][nt], 0,0,0);
        if (s < 6) {
            #pragma unroll
            for (int nt = 0; nt < 4; ++nt)
                bc[nt] = *(const bf16x8*)(W2t + (size_t)(wnc + nt*16 + ln) * HDIM + (k0 + 64) + kq*8);
        }
        a0c = a0n; a1c = a1n;
    }

    // stage-2 epilogue: bias -> out (fp32)
    #pragma unroll
    for (int nt = 0; nt < 4; ++nt) {
        const int n = wnc + nt*16 + ln;
        const float bv = b2[n];
        #pragma unroll
        for (int mt = 0; mt < 2; ++mt) {
            const int rbase = m0 + wm + mt*16 + kq*4;
            #pragma unroll
            for (int r = 0; r < 4; ++r)
                out[(size_t)(rbase + r) * HDIM + n] = acc[mt][nt][r] + bv;
        }
    }
}

extern "C" void kernel_launch(void* const* d_in, const int* in_sizes, int n_in,
                              void* d_out, int out_size, void* d_ws, size_t ws_size,
                              hipStream_t stream) {
    (void)in_sizes; (void)n_in; (void)ws_size;
    const float* x        = (const float*)d_in[0];   // [4096,256]
    const float* pos      = (const float*)d_in[1];   // [4096,3]
    const float* x_skip   = (const float*)d_in[3];   // [16384,128]
    const float* pos_skip = (const float*)d_in[4];   // [16384,3]
    const float* W1       = (const float*)d_in[6];   // [384,256]
    const float* b1       = (const float*)d_in[7];   // [256]
    const float* W2       = (const float*)d_in[8];   // [256,256]
    const float* b2       = (const float*)d_in[9];   // [256]
    float* out = (float*)d_out;

    char* ws = (char*)d_ws;
    __hip_bfloat16* W1t = (__hip_bfloat16*)(ws);             //   196,608
    __hip_bfloat16* W2t = (__hip_bfloat16*)(ws + 196608);    //   131,072
    __hip_bfloat16* Aq  = (__hip_bfloat16*)(ws + 327680);    // 1,048,576 (16384 x 32 bf16)
    __hip_bfloat16* Pv  = (__hip_bfloat16*)(ws + 1376256);   //   262,144 ( 4096 x 32 bf16)
                                                             // total ~1.64 MB

    prep_tail_kernel<<<(PAQ + 255)/256, 256, 0, stream>>>(
        W1, W2, pos, pos_skip, W1t, W2t, Aq, Pv, out, out_size);
    mega_kernel<<<M_Q/QB, 512, 0, stream>>>(
        (const __bf16*)Aq, (const __bf16*)Pv, pos, pos_skip, x, x_skip,
        (const __bf16*)W1t, (const __bf16*)W2t, b1, b2, out);
}

// Round 13
// 139.301 us; speedup vs baseline: 1.0786x; 1.0430x over previous
//
#include <hip/hip_runtime.h>
#include <hip/hip_bf16.h>

#define N_PTS  4096
#define M_Q    16384
#define C_IN   256
#define C_SKIP 128
#define C_H    384      // C_IN + C_SKIP
#define HDIM   256
#define QB     64       // queries per block -> 256 blocks = 1/CU
#define CANDMAX 24
#define EPSW   4e-3f    // capture window >= 2x worst-case MFMA d' error (~4e-4)

typedef __bf16 bf16x8 __attribute__((ext_vector_type(8)));
typedef float  f32x4  __attribute__((ext_vector_type(4)));

// prep segment boundaries
#define PW1  (C_H*HDIM)                    //  98304
#define PW2  (PW1 + HDIM*HDIM)             // 163840
#define PPV  (PW2 + N_PTS)                 // 167936
#define PAQ  (PPV + M_Q)                   // 184320

__device__ __forceinline__ unsigned short bfbits(float v) {
    __hip_bfloat16 b = __float2bfloat16(v);
    return *(unsigned short*)&b;
}
__device__ __forceinline__ float bff(unsigned short u) {
    __hip_bfloat16 b = *(__hip_bfloat16*)&u;
    return __bfloat162float(b);
}
// 3-way bf16 split: v = h + m + l + O(2^-27 v)
__device__ __forceinline__ void split3(float v, unsigned short& h,
                                       unsigned short& m, unsigned short& l) {
    h = bfbits(v);       float r  = v - bff(h);
    m = bfbits(r);       float r2 = r - bff(m);
    l = bfbits(r2);
}

// ---- Phase 0: prep — weights transpose, A/B distance K-vectors, out tail ---
// A-vec (per query q): 21 slots pairing with B-vec (per point p) so that
// mfma(A,B) = |p|^2 - 2 q.p in ~f32 accuracy:
//   per dim d: A[6d+..]=[ah,ah,am,ah,al,am], B[6d+..]=[bh,bm,bh,bl,bh,bm]
//   (a=-2q_d 3-split, b=p_d 3-split; missing cross terms ~2^-27)
//   k=18..20: A=[1,1,1], B=[pw_h,pw_m,pw_l]  (pw=|p|^2). k=21..31 zero.
__global__ __launch_bounds__(256) void prep_tail_kernel(
        const float* __restrict__ W1, const float* __restrict__ W2,
        const float* __restrict__ pos, const float* __restrict__ pos_skip,
        __hip_bfloat16* __restrict__ W1t, __hip_bfloat16* __restrict__ W2t,
        __hip_bfloat16* __restrict__ Aq, __hip_bfloat16* __restrict__ Pv,
        float* __restrict__ out, int out_size) {
    const int i = blockIdx.x * 256 + threadIdx.x;
    if (i < PW1) {
        const int k = i / HDIM, n = i % HDIM;
        W1t[n * C_H + k] = __float2bfloat16(W1[i]);
    } else if (i < PW2) {
        const int j = i - PW1;
        const int k = j / HDIM, n = j % HDIM;
        W2t[n * HDIM + k] = __float2bfloat16(W2[j]);
    } else if (i < PPV) {
        const int j = i - PW2;                       // point j -> Pv row
        const float px = pos[j*3+0], py = pos[j*3+1], pz = pos[j*3+2];
        const float pw = px*px + py*py + pz*pz;
        union { unsigned short u[32]; uint4 q[4]; } S;
        #pragma unroll
        for (int k = 0; k < 32; ++k) S.u[k] = 0;
        const float pd[3] = {px, py, pz};
        #pragma unroll
        for (int d = 0; d < 3; ++d) {
            unsigned short bh, bm, bl; split3(pd[d], bh, bm, bl);
            S.u[6*d+0] = bh; S.u[6*d+1] = bm; S.u[6*d+2] = bh;
            S.u[6*d+3] = bl; S.u[6*d+4] = bh; S.u[6*d+5] = bm;
        }
        unsigned short wh, wm, wl; split3(pw, wh, wm, wl);
        S.u[18] = wh; S.u[19] = wm; S.u[20] = wl;
        uint4* dst = (uint4*)(Pv + (size_t)j * 32);
        dst[0] = S.q[0]; dst[1] = S.q[1]; dst[2] = S.q[2]; dst[3] = S.q[3];
    } else if (i < PAQ) {
        const int j = i - PPV;                       // query j -> Aq row
        const float ax = -2.0f * pos_skip[j*3+0];
        const float ay = -2.0f * pos_skip[j*3+1];
        const float az = -2.0f * pos_skip[j*3+2];
        union { unsigned short u[32]; uint4 q[4]; } S;
        #pragma unroll
        for (int k = 0; k < 32; ++k) S.u[k] = 0;
        const float ad[3] = {ax, ay, az};
        #pragma unroll
        for (int d = 0; d < 3; ++d) {
            unsigned short ah, am, al; split3(ad[d], ah, am, al);
            S.u[6*d+0] = ah; S.u[6*d+1] = ah; S.u[6*d+2] = am;
            S.u[6*d+3] = ah; S.u[6*d+4] = al; S.u[6*d+5] = am;
        }
        const unsigned short one = bfbits(1.0f);
        S.u[18] = one; S.u[19] = one; S.u[20] = one;
        uint4* dst = (uint4*)(Aq + (size_t)j * 32);
        dst[0] = S.q[0]; dst[1] = S.q[1]; dst[2] = S.q[2]; dst[3] = S.q[3];
    }
    // output tail: pos_skip passthrough + zero pad
    if (i < M_Q * 3) out[(size_t)M_Q * HDIM + i] = pos_skip[i];
    const int zbase = M_Q * HDIM + M_Q * 3;
    if (zbase + i < out_size) out[zbase + i] = 0.0f;
}

// ---- Mega kernel v6 (r8, best measured): MFMA-kNN + gather + MLP -----------
// 64 q/block, 512 thr = 8 waves, grid 256. Wave w owns points [w*512,(w+1)*512).
// P1: 128 MFMAs (4 q-tiles x 32 p-tiles, C=0) -> values-only top3 (med3/min),
//     butterfly + wave0 merge -> bb2G[q] (3rd-best approx value).
// P2: MFMA recompute; capture d' <= bb2G+EPSW into per-query LDS lists.
// P3: wave0 exact f32 select on candidates (reference d2 formula + lex
//     tie-break) -> idxL/wnL.  Then gather h -> GEMM1 -> hid -> GEMM2 -> out.
__global__ __launch_bounds__(512) void mega_kernel(
        const __bf16* __restrict__ Aq, const __bf16* __restrict__ Pv,
        const float* __restrict__ pos, const float* __restrict__ pos_skip,
        const float* __restrict__ x, const float* __restrict__ x_skip,
        const __bf16* __restrict__ W1t, const __bf16* __restrict__ W2t,
        const float* __restrict__ b1, const float* __restrict__ b2,
        float* __restrict__ out) {
    __shared__ __align__(16) char smem[51968];
    __hip_bfloat16* h     = (__hip_bfloat16*)smem;            // [64][392] 50.2K (gather..GEMM1)
    __hip_bfloat16* hid   = (__hip_bfloat16*)smem;            // [64][264] overlays h post-GEMM1
    float*          candD = (float*)smem;                     // [8][64][3] 6K   (P1/merge)
    int*            candI = (int*)  (smem + 6144);            // [64][24]  6K   (P2/P3)
    int*            candC = (int*)  (smem + 12288);           // [64]      256B
    float*          bb2G  = (float*)(smem + 50176);           // [64]
    int*            idxL  = (int*)  (smem + 50432);           // [192]
    float*          wnL   = (float*)(smem + 51200);           // [192]

    const int t    = threadIdx.x;
    const int m0   = blockIdx.x * QB;
    const int wave = t >> 6, lane = t & 63;
    const int ln = lane & 15, kq = lane >> 4;

    if (t < 64) candC[t] = 0;

    // x_skip preload (consumed in gather phase)
    float4 skipv[4];
    #pragma unroll
    for (int p = 0; p < 4; ++p) {
        const int g = p * 512 + t;
        const int r = g >> 5, c = (g & 31) * 4;
        skipv[p] = *(const float4*)(x_skip + (size_t)(m0 + r) * C_SKIP + c);
    }

    // resident A-frags: 4 q-tiles x 8 bf16
    bf16x8 afq[4];
    #pragma unroll
    for (int qt = 0; qt < 4; ++qt)
        afq[qt] = *(const bf16x8*)(Aq + (size_t)(m0 + qt*16 + ln) * 32 + kq*8);

    const f32x4 zacc = {0.0f, 0.0f, 0.0f, 0.0f};
    const int ptbase = wave * 32;                  // p-tile base (16 pts each)

    // ---- Phase 1: MFMA distances, values-only top3 ----
    float b0_[4][4], b1_[4][4], b2_[4][4];
    #pragma unroll
    for (int qt = 0; qt < 4; ++qt)
        #pragma unroll
        for (int r = 0; r < 4; ++r) { b0_[qt][r]=3e38f; b1_[qt][r]=3e38f; b2_[qt][r]=3e38f; }

    bf16x8 bcur = *(const bf16x8*)(Pv + (size_t)(ptbase*16 + ln) * 32 + kq*8);
    for (int pt = 0; pt < 32; ++pt) {
        bf16x8 bnext;
        if (pt < 31)
            bnext = *(const bf16x8*)(Pv + (size_t)((ptbase+pt+1)*16 + ln) * 32 + kq*8);
        #pragma unroll
        for (int qt = 0; qt < 4; ++qt) {
            const f32x4 d = __builtin_amdgcn_mfma_f32_16x16x32_bf16(afq[qt], bcur, zacc, 0,0,0);
            #pragma unroll
            for (int r = 0; r < 4; ++r) {
                b2_[qt][r] = __builtin_amdgcn_fmed3f(d[r], b1_[qt][r], b2_[qt][r]);
                b1_[qt][r] = __builtin_amdgcn_fmed3f(d[r], b0_[qt][r], b1_[qt][r]);
                b0_[qt][r] = fminf(b0_[qt][r], d[r]);
            }
        }
        bcur = bnext;
    }
    // butterfly merge across the 16 lanes (ln) sharing each row-group
    #pragma unroll
    for (int qt = 0; qt < 4; ++qt)
        #pragma unroll
        for (int r = 0; r < 4; ++r) {
            float v0 = b0_[qt][r], v1 = b1_[qt][r], v2 = b2_[qt][r];
            #pragma unroll
            for (int m = 1; m <= 8; m <<= 1) {
                const float o0 = __shfl_xor(v0, m), o1 = __shfl_xor(v1, m), o2 = __shfl_xor(v2, m);
                const float mx  = fmaxf(v0, o0);
                const float z0  = fminf(v0, o0);
                const float mn1 = fminf(v1, o1);
                const float mn2 = fminf(v2, o2);
                v0 = z0;
                v1 = fminf(mx, mn1);
                v2 = __builtin_amdgcn_fmed3f(mx, mn1, mn2);
            }
            b0_[qt][r] = v0; b1_[qt][r] = v1; b2_[qt][r] = v2;
        }
    if (ln == 0) {
        #pragma unroll
        for (int qt = 0; qt < 4; ++qt)
            #pragma unroll
            for (int r = 0; r < 4; ++r) {
                const int base = (wave*64 + qt*16 + kq*4 + r) * 3;
                candD[base+0] = b0_[qt][r];
                candD[base+1] = b1_[qt][r];
                candD[base+2] = b2_[qt][r];
            }
    }
    __syncthreads();

    // ---- wave0: merge 8 wave-triples -> bb2G (3rd-best value) ----
    if (t < 64) {
        float B0 = 3e38f, B1 = 3e38f, B2 = 3e38f;
        #pragma unroll
        for (int ww = 0; ww < 8; ++ww) {
            const int base = (ww*64 + t) * 3;
            #pragma unroll
            for (int k = 0; k < 3; ++k) {
                const float v = candD[base+k];
                B2 = __builtin_amdgcn_fmed3f(v, B1, B2);
                B1 = __builtin_amdgcn_fmed3f(v, B0, B1);
                B0 = fminf(B0, v);
            }
        }
        bb2G[t] = B2;
    }
    __syncthreads();

    // ---- Phase 2: recompute + capture candidates within window ----
    float thr[4][4];
    #pragma unroll
    for (int qt = 0; qt < 4; ++qt)
        #pragma unroll
        for (int r = 0; r < 4; ++r)
            thr[qt][r] = bb2G[qt*16 + kq*4 + r] + EPSW;

    bcur = *(const bf16x8*)(Pv + (size_t)(ptbase*16 + ln) * 32 + kq*8);
    for (int pt = 0; pt < 32; ++pt) {
        bf16x8 bnext;
        if (pt < 31)
            bnext = *(const bf16x8*)(Pv + (size_t)((ptbase+pt+1)*16 + ln) * 32 + kq*8);
        const int pidx = (ptbase + pt) * 16 + ln;
        #pragma unroll
        for (int qt = 0; qt < 4; ++qt) {
            const f32x4 d = __builtin_amdgcn_mfma_f32_16x16x32_bf16(afq[qt], bcur, zacc, 0,0,0);
            const bool h0 = d[0] <= thr[qt][0], h1 = d[1] <= thr[qt][1];
            const bool h2 = d[2] <= thr[qt][2], h3 = d[3] <= thr[qt][3];
            if (__builtin_expect(h0|h1|h2|h3, 0)) {
                #pragma unroll
                for (int r = 0; r < 4; ++r) {
                    if (d[r] <= thr[qt][r]) {
                        const int row = qt*16 + kq*4 + r;
                        const int n = atomicAdd(&candC[row], 1);
                        if (n < CANDMAX) candI[row*CANDMAX + n] = pidx;
                    }
                }
            }
        }
        bcur = bnext;
    }
    __syncthreads();

    // ---- Phase 3: exact f32 select on candidates (wave0, lane = query) ----
    if (t < 64) {
        const int q = m0 + t;
        const float qx = pos_skip[q*3+0], qy = pos_skip[q*3+1], qz = pos_skip[q*3+2];
        int cnt = candC[t]; if (cnt > CANDMAX) cnt = CANDMAX;
        float e0 = 3e38f, e1 = 3e38f, e2 = 3e38f;
        int   i0 = 0x7fffffff, i1 = 0x7fffffff, i2 = 0x7fffffff;
        for (int c = 0; c < cnt; ++c) {
            const int j = candI[t*CANDMAX + c];
            const float dx = qx - pos[j*3+0];
            const float dy = qy - pos[j*3+1];
            const float dz = qz - pos[j*3+2];
            const float d2 = dx*dx + dy*dy + dz*dz;    // exact reference d2k
            // lexicographic (d2, idx) insert -> reference tie-break (lowest idx)
            const bool c2 = (d2 < e2) || (d2 == e2 && j < i2);
            if (c2) {
                const bool c1 = (d2 < e1) || (d2 == e1 && j < i1);
                if (c1) {
                    e2 = e1; i2 = i1;
                    const bool c0 = (d2 < e0) || (d2 == e0 && j < i0);
                    if (c0) { e1 = e0; i1 = i0; e0 = d2; i0 = j; }
                    else    { e1 = d2; i1 = j; }
                } else { e2 = d2; i2 = j; }
            }
        }
        const float w0 = 1.0f / fmaxf(e0, 1e-16f);
        const float w1 = 1.0f / fmaxf(e1, 1e-16f);
        const float w2 = 1.0f / fmaxf(e2, 1e-16f);
        const float inv = 1.0f / (w0 + w1 + w2);
        idxL[t*3+0] = i0; idxL[t*3+1] = i1; idxL[t*3+2] = i2;
        wnL[t*3+0] = w0*inv; wnL[t*3+1] = w1*inv; wnL[t*3+2] = w2*inv;
    }
    __syncthreads();   // cand region dead; h arena free

    const int wm  = (wave >> 2) * 32;   // 2 m-wave-rows of 32
    const int wnc = (wave & 3) * 64;    // 4 n-wave-cols of 64

    // ---- weight frag prefetch (k=0,32): in flight during gather ----
    bf16x8 bfA[4], bfB[4];
    #pragma unroll
    for (int nt = 0; nt < 4; ++nt) {
        bfA[nt] = *(const bf16x8*)(W1t + (size_t)(wnc + nt*16 + ln) * C_H +  0 + kq*8);
        bfB[nt] = *(const bf16x8*)(W1t + (size_t)(wnc + nt*16 + ln) * C_H + 32 + kq*8);
    }

    // ---- gather-interp + skip concat into h ----
    #pragma unroll
    for (int p = 0; p < 4; ++p) {
        const int g = p * 512 + t;
        const int r = g >> 5, c = (g & 31) * 4;
        union { __hip_bfloat162 v2[2]; uint2 u; } pk;
        pk.v2[0].x = __float2bfloat16(skipv[p].x); pk.v2[0].y = __float2bfloat16(skipv[p].y);
        pk.v2[1].x = __float2bfloat16(skipv[p].z); pk.v2[1].y = __float2bfloat16(skipv[p].w);
        *(uint2*)&h[(size_t)r * 392 + C_IN + c] = pk.u;
    }
    #pragma unroll 4
    for (int p = 0; p < 8; ++p) {
        const int g = p * 512 + t;                 // 0..4095
        const int r = g >> 6, c = (g & 63) * 4;
        const int   i0 = idxL[r*3+0], i1 = idxL[r*3+1], i2 = idxL[r*3+2];
        const float w0 = wnL[r*3+0],  w1 = wnL[r*3+1],  w2 = wnL[r*3+2];
        const float4 v0 = *(const float4*)(x + (size_t)i0 * C_IN + c);
        const float4 v1 = *(const float4*)(x + (size_t)i1 * C_IN + c);
        const float4 v2 = *(const float4*)(x + (size_t)i2 * C_IN + c);
        union { __hip_bfloat162 v2_[2]; uint2 u; } pk;
        pk.v2_[0].x = __float2bfloat16(w0*v0.x + w1*v1.x + w2*v2.x);
        pk.v2_[0].y = __float2bfloat16(w0*v0.y + w1*v1.y + w2*v2.y);
        pk.v2_[1].x = __float2bfloat16(w0*v0.z + w1*v1.z + w2*v2.z);
        pk.v2_[1].y = __float2bfloat16(w0*v0.w + w1*v1.w + w2*v2.w);
        *(uint2*)&h[(size_t)r * 392 + c] = pk.u;
    }
    __syncthreads();   // h complete

    f32x4 acc[2][4] = {};

    // ---- stage 1: hid = relu(h @ W1t^T + b1), K=384, barrier-free ----
    #pragma unroll
    for (int s = 0; s < 12; ++s) {
        const int k0 = s * 32;
        bf16x8* bc = (s & 1) ? bfB : bfA;
        const bf16x8 a0 = *(const bf16x8*)&h[(size_t)(wm +      ln) * 392 + k0 + kq*8];
        const bf16x8 a1 = *(const bf16x8*)&h[(size_t)(wm + 16 + ln) * 392 + k0 + kq*8];
        #pragma unroll
        for (int nt = 0; nt < 4; ++nt)
            acc[0][nt] = __builtin_amdgcn_mfma_f32_16x16x32_bf16(a0, bc[nt], acc[0][nt], 0,0,0);
        #pragma unroll
        for (int nt = 0; nt < 4; ++nt)
            acc[1][nt] = __builtin_amdgcn_mfma_f32_16x16x32_bf16(a1, bc[nt], acc[1][nt], 0,0,0);
        if (s < 10) {
            #pragma unroll
            for (int nt = 0; nt < 4; ++nt)
                bc[nt] = *(const bf16x8*)(W1t + (size_t)(wnc + nt*16 + ln) * C_H + (k0 + 64) + kq*8);
        } else {
            #pragma unroll
            for (int nt = 0; nt < 4; ++nt)
                bc[nt] = *(const bf16x8*)(W2t + (size_t)(wnc + nt*16 + ln) * HDIM + (s - 10) * 32 + kq*8);
        }
    }
    __syncthreads();   // all h reads done -> arena reusable as hid

    // stage-1 epilogue: bias + relu -> hid (overlays h), reset acc
    #pragma unroll
    for (int nt = 0; nt < 4; ++nt) {
        const int n = wnc + nt*16 + ln;
        const float bv = b1[n];
        #pragma unroll
        for (int mt = 0; mt < 2; ++mt) {
            const int rbase = wm + mt*16 + kq*4;
            #pragma unroll
            for (int r = 0; r < 4; ++r) {
                const float v = fmaxf(acc[mt][nt][r] + bv, 0.0f);
                hid[(size_t)(rbase + r) * 264 + n] = __float2bfloat16(v);
                acc[mt][nt][r] = 0.0f;
            }
        }
    }
    __syncthreads();

    // ---- stage 2: out = hid @ W2t^T + b2, K=256, barrier-free ----
    #pragma unroll
    for (int s = 0; s < 8; ++s) {
        const int k0 = s * 32;
        bf16x8* bc = (s & 1) ? bfB : bfA;
        const bf16x8 a0 = *(const bf16x8*)&hid[(size_t)(wm +      ln) * 264 + k0 + kq*8];
        const bf16x8 a1 = *(const bf16x8*)&hid[(size_t)(wm + 16 + ln) * 264 + k0 + kq*8];
        #pragma unroll
        for (int nt = 0; nt < 4; ++nt)
            acc[0][nt] = __builtin_amdgcn_mfma_f32_16x16x32_bf16(a0, bc[nt], acc[0][nt], 0,0,0);
        #pragma unroll
        for (int nt = 0; nt < 4; ++nt)
            acc[1][nt] = __builtin_amdgcn_mfma_f32_16x16x32_bf16(a1, bc[nt], acc[1][nt], 0,0,0);
        if (s < 6) {
            #pragma unroll
            for (int nt = 0; nt < 4; ++nt)
                bc[nt] = *(const bf16x8*)(W2t + (size_t)(wnc + nt*16 + ln) * HDIM + (k0 + 64) + kq*8);
        }
    }

    // stage-2 epilogue: bias -> out (fp32)
    #pragma unroll
    for (int nt = 0; nt < 4; ++nt) {
        const int n = wnc + nt*16 + ln;
        const float bv = b2[n];
        #pragma unroll
        for (int mt = 0; mt < 2; ++mt) {
            const int rbase = m0 + wm + mt*16 + kq*4;
            #pragma unroll
            for (int r = 0; r < 4; ++r)
                out[(size_t)(rbase + r) * HDIM + n] = acc[mt][nt][r] + bv;
        }
    }
}

extern "C" void kernel_launch(void* const* d_in, const int* in_sizes, int n_in,
                              void* d_out, int out_size, void* d_ws, size_t ws_size,
                              hipStream_t stream) {
    (void)in_sizes; (void)n_in; (void)ws_size;
    const float* x        = (const float*)d_in[0];   // [4096,256]
    const float* pos      = (const float*)d_in[1];   // [4096,3]
    const float* x_skip   = (const float*)d_in[3];   // [16384,128]
    const float* pos_skip = (const float*)d_in[4];   // [16384,3]
    const float* W1       = (const float*)d_in[6];   // [384,256]
    const float* b1       = (const float*)d_in[7];   // [256]
    const float* W2       = (const float*)d_in[8];   // [256,256]
    const float* b2       = (const float*)d_in[9];   // [256]
    float* out = (float*)d_out;

    char* ws = (char*)d_ws;
    __hip_bfloat16* W1t = (__hip_bfloat16*)(ws);             //   196,608
    __hip_bfloat16* W2t = (__hip_bfloat16*)(ws + 196608);    //   131,072
    __hip_bfloat16* Aq  = (__hip_bfloat16*)(ws + 327680);    // 1,048,576 (16384 x 32 bf16)
    __hip_bfloat16* Pv  = (__hip_bfloat16*)(ws + 1376256);   //   262,144 ( 4096 x 32 bf16)
                                                             // total ~1.64 MB

    prep_tail_kernel<<<(PAQ + 255)/256, 256, 0, stream>>>(
        W1, W2, pos, pos_skip, W1t, W2t, Aq, Pv, out, out_size);
    mega_kernel<<<M_Q/QB, 512, 0, stream>>>(
        (const __bf16*)Aq, (const __bf16*)Pv, pos, pos_skip, x, x_skip,
        (const __bf16*)W1t, (const __bf16*)W2t, b1, b2, out);
}